// Round 6
// baseline (1948.108 us; speedup 1.0000x reference)
//
#include <hip/hip_runtime.h>
#include <stdint.h>

#define BATCH  1024
#define SEQLEN 15
#define NGATE  2048
#define NVOCAB 11998
#define FEATS  4096

typedef __attribute__((ext_vector_type(8)))  short  s8v;     // 8 bf16 bit patterns
typedef __attribute__((ext_vector_type(16))) float  f32x16;  // 32x32 MFMA acc
typedef __attribute__((ext_vector_type(8)))  unsigned short us8;

__device__ __forceinline__ unsigned short f2bf(float f) {
    unsigned u = __float_as_uint(f);
    u += 0x7FFFu + ((u >> 16) & 1u);
    return (unsigned short)(u >> 16);
}
__device__ __forceinline__ float bf2f(unsigned short h) {
    return __uint_as_float(((unsigned)h) << 16);
}
struct bfpair { unsigned short hi, lo; };
__device__ __forceinline__ bfpair split2v(float v) {
    bfpair r;
    r.hi = f2bf(v);
    r.lo = f2bf(v - bf2f(r.hi));
    return r;
}
__device__ __forceinline__ void split8(const float* __restrict__ s, us8& vh, us8& vl) {
    #pragma unroll
    for (int e = 0; e < 8; ++e) {
        bfpair q = split2v(s[e]);
        vh[e] = q.hi; vl[e] = q.lo;
    }
}
__device__ __forceinline__ int imin(int a, int b) { return a < b ? a : b; }

// async 16B-per-lane global->LDS; LDS dest = wave-uniform base, lane i lands at base + i*16
__device__ __forceinline__ void async_cp16(const void* g, void* l) {
    __builtin_amdgcn_global_load_lds(
        (const __attribute__((address_space(1))) unsigned int*)g,
        (__attribute__((address_space(3))) unsigned int*)l, 16, 0, 0);
}

// ---------------------------------------------------------------------------
// prep: Wcat blocked [128 kc][2048 row][8] = split([W_ih | W_hh]); bsum
// ---------------------------------------------------------------------------
__global__ void prep_wcat_blk(const float* __restrict__ W_ih, const float* __restrict__ W_hh,
                              const float* __restrict__ b_ih, const float* __restrict__ b_hh,
                              unsigned short* __restrict__ hi, unsigned short* __restrict__ lo,
                              float* __restrict__ bsum) {
    int idx = blockIdx.x * 256 + threadIdx.x;   // 128*2048
    int kc = idx >> 11, row = idx & 2047;
    int k = kc << 3;
    const float* src = (k < 512) ? (W_ih + (size_t)row * 512 + k)
                                 : (W_hh + (size_t)row * 512 + (k - 512));
    us8 vh, vl; split8(src, vh, vl);
    *(us8*)(hi + (size_t)idx * 8) = vh;
    *(us8*)(lo + (size_t)idx * 8) = vl;
    if (idx < NGATE) bsum[idx] = b_ih[idx] + b_hh[idx];
}

// src [R][K] fp32 -> hi/lo [K/8][R][8] bf16. grid: (ceil(R/256), K/8)
__global__ void prep_blk(const float* __restrict__ src,
                         unsigned short* __restrict__ hi, unsigned short* __restrict__ lo,
                         int R, int K) {
    int row = blockIdx.x * 256 + threadIdx.x;
    if (row >= R) return;
    int kc = blockIdx.y;
    us8 vh, vl; split8(src + (size_t)row * K + (kc << 3), vh, vl);
    size_t o = ((size_t)kc * R + row) * 8;
    *(us8*)(hi + o) = vh;
    *(us8*)(lo + o) = vl;
}

// ---------------------------------------------------------------------------
// Split-bf16 MFMA NT GEMM body, double-buffered 16-deep K pipeline.
// Operands pre-split bf16, K8-blocked [kc][rows][8]. 128x128 block tile,
// 4 waves (2x2 of 64x64), 32x32x16 bf16 MFMA, 3-product split (hh+hl+lh).
// LDS: 2 bufs x [4 arr][2 kc][128 row][8] = 32 KB; prefetch it+1 after the
// barrier, consume it -> loads land during the MFMA phase.
// MODE 3: raw fp32 C store (+ blockIdx.z split-K chunk, czstride elems)
// MODE 2: fused bias + per-row argmax via packed u64 atomicMax
// AEMB:   blockIdx.z==0 stages A from emb[word[b]] (word from packedR/START)
// ---------------------------------------------------------------------------
template<int MODE, int AEMB, int FIRST>
__device__ __forceinline__ void gemm_body(
    const unsigned short* __restrict__ Ahi, const unsigned short* __restrict__ Alo, int aRows,
    const unsigned short* __restrict__ Bhi, const unsigned short* __restrict__ Blo, int bRows,
    const float* __restrict__ emb, const unsigned long long* __restrict__ packedR,
    const float* __restrict__ bias,
    float* __restrict__ C, int ldc,
    unsigned long long* __restrict__ packed,
    int K, size_t akstride, size_t bkstride, size_t czstride,
    int bm, int bn)
{
    __shared__ short smem[2 * 8192];   // [buf][arr(4)][kc(2)][row(128)][8]
    const int tid = threadIdx.x;
    const int lane = tid & 63, wave = tid >> 6;
    const int wr = (wave & 1) * 64, wc = (wave >> 1) * 64;
    const int col = lane & 31, kh = lane >> 5;

    const int kz = blockIdx.z;
    Bhi += (size_t)kz * bkstride;  Blo += (size_t)kz * bkstride;
    const bool embp = AEMB && (kz == 0);
    if (!embp) { Ahi += (size_t)kz * akstride; Alo += (size_t)kz * akstride; }
    if (MODE == 3) C += (size_t)kz * czstride;

    // emb-path per-thread constants (thread -> (row, kc parity))
    const float* embrow = nullptr;
    int arow = 0, akcp = 0;
    if (embp) {
        arow = tid >> 1; akcp = tid & 1;
        int w = 1;
        if (!FIRST) {
            unsigned long long p = packedR[bm + arow];
            w = (int)(0xFFFFFFFFu - (unsigned)(p & 0xFFFFFFFFull)) + 2;
        }
        embrow = emb + (size_t)w * 512 + akcp * 8;
    }

    const int nIter = K >> 4;
    f32x16 acc[2][2] = {};

    auto stage = [&](int it) {
        const int kcg = it * 2;
        short* base = smem + (it & 1) * 8192;
        if (!embp) {
            const unsigned short* gsrc = (wave == 0) ? Ahi : (wave == 1) ? Alo
                                       : (wave == 2) ? Bhi : Blo;
            const int rows = (wave < 2) ? aRows : bRows;
            const bool isB = (wave >= 2);
            short* abase = base + wave * 2048;
            #pragma unroll
            for (int p = 0; p < 4; ++p) {
                int kc_l = p >> 1, rh = p & 1;
                int rl = rh * 64 + lane;
                int grow = isB ? imin(bn + rl, rows - 1) : (bm + rl);
                size_t g = ((size_t)(kcg + kc_l) * rows + grow) * 8;
                async_cp16(gsrc + g, abase + (kc_l * 128 + rh * 64) * 8);
            }
        } else {
            #pragma unroll
            for (int p = 0; p < 2; ++p) {
                int s = wave * 2 + p;
                int arr = s >> 2, kc_l = (s >> 1) & 1, rh = s & 1;
                const unsigned short* gsrc = arr ? Blo : Bhi;
                int rl = rh * 64 + lane;
                int grow = imin(bn + rl, bRows - 1);
                size_t g = ((size_t)(kcg + kc_l) * bRows + grow) * 8;
                async_cp16(gsrc + g, base + (2 + arr) * 2048 + (kc_l * 128 + rh * 64) * 8);
            }
            float4 f0 = *(const float4*)(embrow + kcg * 8);
            float4 f1 = *(const float4*)(embrow + kcg * 8 + 4);
            float fb[8] = {f0.x, f0.y, f0.z, f0.w, f1.x, f1.y, f1.z, f1.w};
            us8 vh, vl;
            #pragma unroll
            for (int e = 0; e < 8; ++e) {
                bfpair q = split2v(fb[e]);
                vh[e] = q.hi; vl[e] = q.lo;
            }
            short* d = base + (akcp * 128 + arow) * 8;
            *(us8*)(d) = vh;
            *(us8*)(d + 2048) = vl;
        }
    };

    auto consume = [&](int it) {
        short* base = smem + (it & 1) * 8192;
        const int off = kh * 1024;
        const short* pAhi = base + off;
        const short* pAlo = base + 2048 + off;
        const short* pBhi = base + 4096 + off;
        const short* pBlo = base + 6144 + off;
        s8v ah0 = *(const s8v*)(pAhi + (wr + col) * 8);
        s8v ah1 = *(const s8v*)(pAhi + (wr + 32 + col) * 8);
        s8v al0 = *(const s8v*)(pAlo + (wr + col) * 8);
        s8v al1 = *(const s8v*)(pAlo + (wr + 32 + col) * 8);
        s8v bh0 = *(const s8v*)(pBhi + (wc + col) * 8);
        s8v bh1 = *(const s8v*)(pBhi + (wc + 32 + col) * 8);
        s8v bl0 = *(const s8v*)(pBlo + (wc + col) * 8);
        s8v bl1 = *(const s8v*)(pBlo + (wc + 32 + col) * 8);
        acc[0][0] = __builtin_amdgcn_mfma_f32_32x32x16_bf16(ah0, bh0, acc[0][0], 0, 0, 0);
        acc[0][1] = __builtin_amdgcn_mfma_f32_32x32x16_bf16(ah0, bh1, acc[0][1], 0, 0, 0);
        acc[1][0] = __builtin_amdgcn_mfma_f32_32x32x16_bf16(ah1, bh0, acc[1][0], 0, 0, 0);
        acc[1][1] = __builtin_amdgcn_mfma_f32_32x32x16_bf16(ah1, bh1, acc[1][1], 0, 0, 0);
        acc[0][0] = __builtin_amdgcn_mfma_f32_32x32x16_bf16(ah0, bl0, acc[0][0], 0, 0, 0);
        acc[0][1] = __builtin_amdgcn_mfma_f32_32x32x16_bf16(ah0, bl1, acc[0][1], 0, 0, 0);
        acc[1][0] = __builtin_amdgcn_mfma_f32_32x32x16_bf16(ah1, bl0, acc[1][0], 0, 0, 0);
        acc[1][1] = __builtin_amdgcn_mfma_f32_32x32x16_bf16(ah1, bl1, acc[1][1], 0, 0, 0);
        acc[0][0] = __builtin_amdgcn_mfma_f32_32x32x16_bf16(al0, bh0, acc[0][0], 0, 0, 0);
        acc[0][1] = __builtin_amdgcn_mfma_f32_32x32x16_bf16(al0, bh1, acc[0][1], 0, 0, 0);
        acc[1][0] = __builtin_amdgcn_mfma_f32_32x32x16_bf16(al1, bh0, acc[1][0], 0, 0, 0);
        acc[1][1] = __builtin_amdgcn_mfma_f32_32x32x16_bf16(al1, bh1, acc[1][1], 0, 0, 0);
    };

    stage(0);
    for (int it = 0; it < nIter; ++it) {
        __syncthreads();
        if (it + 1 < nIter) stage(it + 1);
        consume(it);
    }

    // C/D layout (32x32, m74/m101): col = lane&31, row = (reg&3) + 8*(reg>>2) + 4*kh
    if (MODE == 3) {
        #pragma unroll
        for (int i = 0; i < 2; ++i)
            #pragma unroll
            for (int rg = 0; rg < 4; ++rg)
                #pragma unroll
                for (int rr = 0; rr < 4; ++rr) {
                    int reg = rg * 4 + rr;
                    int m = bm + wr + i * 32 + rr + rg * 8 + kh * 4;
                    #pragma unroll
                    for (int j = 0; j < 2; ++j) {
                        int n = bn + wc + j * 32 + col;
                        if (n < bRows) C[(size_t)m * ldc + n] = acc[i][j][reg];
                    }
                }
    } else {
        #pragma unroll
        for (int i = 0; i < 2; ++i)
            #pragma unroll
            for (int rg = 0; rg < 4; ++rg)
                #pragma unroll
                for (int rr = 0; rr < 4; ++rr) {
                    int reg = rg * 4 + rr;
                    int m = bm + wr + i * 32 + rr + rg * 8 + kh * 4;
                    unsigned long long best = 0ull;
                    #pragma unroll
                    for (int j = 0; j < 2; ++j) {
                        int n = bn + wc + j * 32 + col;
                        if (n < bRows) {
                            float v = acc[i][j][reg] + bias[n];
                            unsigned int u   = __float_as_uint(v);
                            unsigned int key = (u & 0x80000000u) ? ~u : (u | 0x80000000u);
                            unsigned long long pk =
                                ((unsigned long long)key << 32) |
                                (unsigned long long)(0xFFFFFFFFu - (unsigned)n);
                            best = (pk > best) ? pk : best;
                        }
                    }
                    #pragma unroll
                    for (int sdist = 1; sdist < 32; sdist <<= 1) {
                        unsigned long long o = __shfl_xor(best, sdist, 64);
                        best = (o > best) ? o : best;
                    }
                    if (col == 0) atomicMax(&packed[m], best);
                }
    }
}

// generic store GEMM (feats split-K, prime gates)
__global__ __launch_bounds__(256) void k_mm(
    const unsigned short* Ahi, const unsigned short* Alo, int aRows,
    const unsigned short* Bhi, const unsigned short* Blo, int bRows,
    float* C, int ldc, int K, size_t aks, size_t bks, size_t czs) {
    gemm_body<3, 0, 0>(Ahi, Alo, aRows, Bhi, Blo, bRows, nullptr, nullptr, nullptr,
                       C, ldc, nullptr, K, aks, bks, czs,
                       blockIdx.y * 128, blockIdx.x * 128);
}
// loop gates: z=0 stages A from emb[word], z=1 async from h slabs
template<int FIRST>
__global__ __launch_bounds__(256) void k_gates_f(
    const unsigned short* h_hi, const unsigned short* h_lo,
    const unsigned short* wcat_hi, const unsigned short* wcat_lo,
    const float* emb, const unsigned long long* packedR,
    float* C) {
    gemm_body<3, 1, FIRST>(h_hi, h_lo, 1024, wcat_hi, wcat_lo, NGATE,
                           emb, packedR, nullptr, C, NGATE, nullptr,
                           512, 0, (size_t)64 * NGATE * 8, (size_t)1024 * NGATE,
                           blockIdx.y * 128, blockIdx.x * 128);
}
// logits + argmax, XCD-swizzled 1D grid of 768 (96 bn-tiles x 8 bm-tiles)
__global__ __launch_bounds__(256) void k_logits_argmax(
    const unsigned short* h_hi, const unsigned short* h_lo,
    const unsigned short* wout_hi, const unsigned short* wout_lo,
    const float* bias, unsigned long long* packed) {
    int id = blockIdx.x;
    int xcd = id & 7, slot = id >> 3;          // blocks round-robin XCDs (heuristic)
    int bn_t = xcd * 12 + (slot % 12);         // 12 bn-tiles (3 MB B) per XCD -> fits L2
    int bm_t = slot / 12;
    gemm_body<2, 0, 0>(h_hi, h_lo, 1024, wout_hi, wout_lo, NVOCAB,
                       nullptr, nullptr, bias, nullptr, 0, packed,
                       512, 0, 0, 0, bm_t * 128, bn_t * 128);
}

// ---------------------------------------------------------------------------
// feats reduce: sum 8 split-K partials + bias, relu, split -> imgv blocked
// ---------------------------------------------------------------------------
__global__ void feats_reduce8(const float* __restrict__ part, const float* __restrict__ bias,
                              unsigned short* __restrict__ hi, unsigned short* __restrict__ lo) {
    int idx = blockIdx.x * 256 + threadIdx.x;   // 1024*64
    int b = idx >> 6, kc = idx & 63;
    int n = kc << 3;
    float v[8];
    #pragma unroll
    for (int e = 0; e < 8; ++e) v[e] = bias[n + e];
    #pragma unroll
    for (int z = 0; z < 8; ++z) {
        const float* s = part + (size_t)z * 1024 * 512 + (size_t)b * 512 + n;
        #pragma unroll
        for (int e = 0; e < 8; ++e) v[e] += s[e];
    }
    us8 vh, vl;
    #pragma unroll
    for (int e = 0; e < 8; ++e) {
        bfpair q = split2v(fmaxf(v[e], 0.f));
        vh[e] = q.hi; vl[e] = q.lo;
    }
    size_t o = ((size_t)kc * 1024 + b) * 8;
    *(us8*)(hi + o) = vh;
    *(us8*)(lo + o) = vl;
}

// ---------------------------------------------------------------------------
// LSTM pointwise; also emits out[b][t-1] from packed (before zeroing it)
// ---------------------------------------------------------------------------
template<bool PRIME>
__global__ void lstm_pw_blk(const float* __restrict__ g0, const float* __restrict__ g1,
                            const float* __restrict__ bsum, float* __restrict__ cbuf,
                            unsigned short* __restrict__ h_hi, unsigned short* __restrict__ h_lo,
                            unsigned long long* __restrict__ packed,
                            int* __restrict__ out, int t) {
    int idx = blockIdx.x * 256 + threadIdx.x;   // 1024*64
    int b = idx >> 6, j8 = idx & 63;
    int j = j8 << 3;
    const float* g = g0 + (size_t)b * NGATE;
    float v[4][8];
    #pragma unroll
    for (int gt = 0; gt < 4; ++gt) {
        const float* s = g + gt * 512 + j;
        const float* bs = bsum + gt * 512 + j;
        #pragma unroll
        for (int e = 0; e < 8; ++e) v[gt][e] = s[e] + bs[e];
    }
    if (g1) {
        const float* h2 = g1 + (size_t)b * NGATE;
        #pragma unroll
        for (int gt = 0; gt < 4; ++gt) {
            const float* s = h2 + gt * 512 + j;
            #pragma unroll
            for (int e = 0; e < 8; ++e) v[gt][e] += s[e];
        }
    }
    float* cb = cbuf + (size_t)b * 512 + j;
    us8 vh, vl;
    #pragma unroll
    for (int e = 0; e < 8; ++e) {
        float si = 1.f / (1.f + expf(-v[0][e]));
        float sf = 1.f / (1.f + expf(-v[1][e]));
        float tg = tanhf(v[2][e]);
        float so = 1.f / (1.f + expf(-v[3][e]));
        float cn = PRIME ? (si * tg) : (sf * cb[e] + si * tg);
        cb[e] = cn;
        bfpair q = split2v(so * tanhf(cn));
        vh[e] = q.hi; vl[e] = q.lo;
    }
    size_t o = ((size_t)j8 * 1024 + b) * 8;
    *(us8*)(h_hi + o) = vh;
    *(us8*)(h_lo + o) = vl;
    if (j8 == 0) {
        if (!PRIME && t > 0) {
            unsigned long long p = packed[b];
            out[b * SEQLEN + (t - 1)] = (int)(0xFFFFFFFFu - (unsigned)(p & 0xFFFFFFFFull));
        }
        packed[b] = 0ull;
    }
}

__global__ void final_out(const unsigned long long* __restrict__ packed, int* __restrict__ out) {
    int b = blockIdx.x * 256 + threadIdx.x;
    if (b < BATCH) {
        unsigned long long p = packed[b];
        out[b * SEQLEN + (SEQLEN - 1)] = (int)(0xFFFFFFFFu - (unsigned)(p & 0xFFFFFFFFull));
    }
}

extern "C" void kernel_launch(void* const* d_in, const int* in_sizes, int n_in,
                              void* d_out, int out_size, void* d_ws, size_t ws_size,
                              hipStream_t stream) {
    const float* img     = (const float*)d_in[0];
    const float* W_feats = (const float*)d_in[1];
    const float* b_feats = (const float*)d_in[2];
    const float* W_ih    = (const float*)d_in[3];
    const float* W_hh    = (const float*)d_in[4];
    const float* b_ih    = (const float*)d_in[5];
    const float* b_hh    = (const float*)d_in[6];
    const float* emb     = (const float*)d_in[7];
    const float* W_out   = (const float*)d_in[8];
    const float* b_out   = (const float*)d_in[9];
    int* out = (int*)d_out;

    const size_t WCAT_H = (size_t)128 * 2048 * 8;
    const size_t WOUT_H = (size_t)64 * NVOCAB * 8;
    const size_t H_H    = (size_t)64 * 1024 * 8;
    const size_t IMGV_H = (size_t)64 * 1024 * 8;

    char* p = (char*)d_ws;
    unsigned short* wcat_hi = (unsigned short*)p;  p += WCAT_H * 2;
    unsigned short* wcat_lo = (unsigned short*)p;  p += WCAT_H * 2;
    unsigned short* wout_hi = (unsigned short*)p;  p += WOUT_H * 2;
    unsigned short* wout_lo = (unsigned short*)p;  p += WOUT_H * 2;
    unsigned short* h_hi    = (unsigned short*)p;  p += H_H * 2;
    unsigned short* h_lo    = (unsigned short*)p;  p += H_H * 2;
    unsigned short* imgv_hi = (unsigned short*)p;  p += IMGV_H * 2;
    unsigned short* imgv_lo = (unsigned short*)p;  p += IMGV_H * 2;
    float* cbuf             = (float*)p;           p += (size_t)1024 * 512 * 4;
    float* bsum             = (float*)p;           p += (size_t)NGATE * 4;
    unsigned long long* packed = (unsigned long long*)p;  p += (size_t)1024 * 8;
    float* gates0           = (float*)p;           p += (size_t)1024 * NGATE * 4;
    float* gates1           = (float*)p;           p += (size_t)1024 * NGATE * 4;
    // transient blocked feats inputs alias the not-yet-written wout region
    // (imgb 16 MB + wfb 8 MB = 24 MB <= 24.57 MB):
    unsigned short* imgb_hi = wout_hi;
    unsigned short* imgb_lo = imgb_hi + (size_t)512 * 1024 * 8;
    unsigned short* wfb_hi  = imgb_lo + (size_t)512 * 1024 * 8;
    unsigned short* wfb_lo  = wfb_hi  + (size_t)512 * 512 * 8;
    float* partials = gates0;   // 8 x (1024x512) fp32 = gates0+gates1 region

    // ---- one-time prep
    prep_wcat_blk<<<1024, 256, 0, stream>>>(W_ih, W_hh, b_ih, b_hh, wcat_hi, wcat_lo, bsum);
    prep_blk<<<dim3(4, 512), 256, 0, stream>>>(img,     imgb_hi, imgb_lo, 1024, FEATS);
    prep_blk<<<dim3(2, 512), 256, 0, stream>>>(W_feats, wfb_hi,  wfb_lo,  512,  FEATS);

    // feats: partials[z] = img(chunk z) @ W_feats(chunk z)^T, split-K x8
    k_mm<<<dim3(4, 8, 8), 256, 0, stream>>>(
        imgb_hi, imgb_lo, 1024, wfb_hi, wfb_lo, 512,
        partials, 512, 512,
        (size_t)64 * 1024 * 8, (size_t)64 * 512 * 8, (size_t)1024 * 512);
    feats_reduce8<<<256, 256, 0, stream>>>(partials, b_feats, imgv_hi, imgv_lo);

    // feats transients dead -> build blocked W_out in place
    prep_blk<<<dim3(47, 64), 256, 0, stream>>>(W_out, wout_hi, wout_lo, NVOCAB, 512);

    // prime LSTM: gates0 = imgv @ W_ih^T (Wcat kc 0..63)
    k_mm<<<dim3(16, 8, 1), 256, 0, stream>>>(
        imgv_hi, imgv_lo, 1024, wcat_hi, wcat_lo, 2048,
        gates0, NGATE, 512, 0, 0, 0);
    lstm_pw_blk<true><<<256, 256, 0, stream>>>(gates0, nullptr, bsum, cbuf,
                                               h_hi, h_lo, packed, out, 0);

    for (int t = 0; t < SEQLEN; ++t) {
        // gates{0,1}: z=0 = emb(word)@W_ih^T (gather fused), z=1 = h@W_hh^T
        if (t == 0)
            k_gates_f<1><<<dim3(16, 8, 2), 256, 0, stream>>>(
                h_hi, h_lo, wcat_hi, wcat_lo, emb, packed, gates0);
        else
            k_gates_f<0><<<dim3(16, 8, 2), 256, 0, stream>>>(
                h_hi, h_lo, wcat_hi, wcat_lo, emb, packed, gates0);
        lstm_pw_blk<false><<<256, 256, 0, stream>>>(gates0, gates1, bsum, cbuf,
                                                    h_hi, h_lo, packed, out, t);
        k_logits_argmax<<<768, 256, 0, stream>>>(h_hi, h_lo, wout_hi, wout_lo, b_out, packed);
    }
    final_out<<<4, 256, 0, stream>>>(packed, out);
}